// Round 10
// baseline (92.951 us; speedup 1.0000x reference)
//
#include <hip/hip_runtime.h>
#include <hip/hip_bf16.h>

#define N_OBJ   32
#define G_TOTAL 4960      // C(32,3)
#define NPAIR   496       // C(32,2)
#define KTOT    1600      // 3*496 (pairs) + 3*32 (diag) + 16 pad
#define SEG01   0
#define SEG02   496
#define SEG12   992
#define SEGD0   1488
#define SEGD1   1520
#define SEGD2   1552
#define N_FILT  16
#define REL_D   16
#define BATCH   32
#define NQ      512
#define ZSPLIT  5
#define KCH     320       // KTOT / ZSPLIT
#define NIT     10        // KCH / 32

typedef __attribute__((ext_vector_type(8))) short bf16x8;
typedef __attribute__((ext_vector_type(4))) float f32x4;

static __device__ inline unsigned short f2bf(float x) {
    union { float f; unsigned int u; } v; v.f = x;
    unsigned int r = v.u + 0x7fffu + ((v.u >> 16) & 1u);   // RNE
    return (unsigned short)(r >> 16);
}
static __device__ inline void gload_lds16(const void* g, void* l) {
    __builtin_amdgcn_global_load_lds(
        (const __attribute__((address_space(1))) unsigned int*)g,
        (__attribute__((address_space(3))) unsigned int*)(unsigned int)(uintptr_t)l,
        16, 0, 0);
}
// base index of pairs starting with x in lexicographic C(32,2) packing
static __device__ inline int pbase(int x) { return (x * (63 - x)) >> 1; }
// unrank lexicographic 2-combination of 32
static __device__ inline void unrank2(int u, int& x, int& y) {
    for (x = 0; x < 31; x++) { int len = 31 - x; if (u < len) break; u -= len; }
    y = x + 1 + u;
}
static __device__ inline float dot16(float4 a0, float4 a1, float4 a2, float4 a3,
                                     const float* F) {
    float4 f0 = *(const float4*)(F);
    float4 f1 = *(const float4*)(F + 4);
    float4 f2 = *(const float4*)(F + 8);
    float4 f3 = *(const float4*)(F + 12);
    float d = a0.x * f0.x + a0.y * f0.y + a0.z * f0.z + a0.w * f0.w;
    d += a1.x * f1.x + a1.y * f1.y + a1.z * f1.z + a1.w * f1.w;
    d += a2.x * f2.x + a2.y * f2.y + a2.z * f2.z + a2.w * f2.w;
    d += a3.x * f3.x + a3.y * f3.y + a3.z * f3.z + a3.w * f3.w;
    return d;
}

// ===== L1: normw rows (0..511) + folded pairconv (512..583, 4 sub-blocks each) ====
// W01[x,y] = sum_{c>y} exp(sp x*y*c); W02[x,z] = sum_{x<b<z}; W12[y,z] = sum_{a<y}
// total = sum of W01 segment (each combo counted once at its (a,b) pair).
__global__ __launch_bounds__(1024) void k_front(const float* __restrict__ logits,
                                                const float* __restrict__ inputs,
                                                const float* __restrict__ filters,
                                                unsigned short* __restrict__ Wp,
                                                unsigned short* __restrict__ Bp,
                                                int* __restrict__ sem) {
    __shared__ __align__(16) char smem[11648];
    int t = threadIdx.x;
    int role = blockIdx.x;

    if (role < NQ) {
        float* sp  = (float*)smem;             // 32 floats
        float* red = (float*)(smem + 128);     // 8 floats
        float* Wf  = (float*)(smem + 192);     // 1600 floats
        int q = role;
        if (t < N_OBJ) {
            float x = logits[q * N_OBJ + t];
            float ex = __expf(x);
            sp[t] = (x > 15.f) ? x : __logf(1.f + ex);
        }
        __syncthreads();

        // pass A: 1488 independent range-sums, no atomics
#pragma unroll
        for (int rep = 0; rep < 2; rep++) {
            int idx = t + rep * 1024;
            if (idx < 3 * NPAIR) {
                int which = idx / NPAIR;
                int u = idx - which * NPAIR;
                int x, y; unrank2(u, x, y);
                float pxy = sp[x] * sp[y];
                float s = 0.f;
                if (which == 0) {                    // W01: c in (y, 32)
                    for (int c = y + 1; c < 32; c++) s += __expf(pxy * sp[c]);
                } else if (which == 1) {             // W02: b in (x, y)
                    for (int c = x + 1; c < y; c++)  s += __expf(pxy * sp[c]);
                } else {                             // W12: a in [0, x)
                    for (int c = 0; c < x; c++)      s += __expf(pxy * sp[c]);
                }
                Wf[which * NPAIR + u] = s;
            }
        }
        __syncthreads();

        // stage 2 (parallel roles): reduce total | diag marginals | pad zero
        if (t < 512) {
            float lsum = (t < NPAIR) ? Wf[t] : 0.f;
#pragma unroll
            for (int off = 32; off; off >>= 1) lsum += __shfl_down(lsum, off, 64);
            if ((t & 63) == 0) red[t >> 6] = lsum;
        } else if (t < 608) {
            int which = (t - 512) >> 5, idx = t & 31;
            float s = 0.f;
            if (which == 0) {                        // Wd0[a] = sum_{b>a} W01[a,b]
                int base = pbase(idx);
                for (int u = idx + 1; u < 32; u++) s += Wf[SEG01 + base + u - idx - 1];
                Wf[SEGD0 + idx] = s;
            } else if (which == 1) {                 // Wd1[b] = sum_{a<b} W01[a,b]
                for (int a2 = 0; a2 < idx; a2++) s += Wf[SEG01 + pbase(a2) + idx - a2 - 1];
                Wf[SEGD1 + idx] = s;
            } else {                                 // Wd2[c] = sum_{b<c} W12[b,c]
                for (int b2 = 0; b2 < idx; b2++) s += Wf[SEG12 + pbase(b2) + idx - b2 - 1];
                Wf[SEGD2 + idx] = s;
            }
        } else if (t < 624) {
            Wf[1584 + (t - 608)] = 0.f;              // K-pad
        }
        __syncthreads();

        // stage 3: normalize + pack + coalesced row write (800 uints)
        if (t < KTOT / 2) {
            float total = red[0] + red[1] + red[2] + red[3] +
                          red[4] + red[5] + red[6] + red[7];
            float inv = 1.f / total;
            unsigned int pk = (unsigned int)f2bf(Wf[2 * t] * inv) |
                              ((unsigned int)f2bf(Wf[2 * t + 1] * inv) << 16);
            ((unsigned int*)(Wp + (size_t)q * KTOT))[t] = pk;
        }
    } else {
        // ---------- folded pairconv: block covers 4 of the old 256-thread blocks ---
        float* flt = (float*)smem;            // 16*180 floats = 11520 B
        int role2 = role - NQ;                // 0..71
        if (role2 == 0 && t < 64) sem[t] = 0; // zero split-K semaphores (ws is poisoned)
        if (t < 576) {
            int i4 = t * 4;
            int f = i4 / 144;
            int r = i4 - f * 144;
            *(float4*)&flt[f * 180 + (r >> 4) * 20 + (r & 15)] = *(const float4*)(filters + i4);
        }
        __syncthreads();

        int oldbid = role2 * 4 + (t >> 8);    // 0..287
        int tp = t & 255;
        int b = oldbid / 9, ch = oldbid - b * 9;
        int lane = tp & 63, fq = tp >> 6;     // 4 filter-quads x 64 items
        int u = ch * 64 + lane;
        if (u < NPAIR) {
            int x, y; unrank2(u, x, y);
            const float4* rxy = (const float4*)(inputs + (((size_t)b * 32 + x) * 32 + y) * 16);
            const float4* ryx = (const float4*)(inputs + (((size_t)b * 32 + y) * 32 + x) * 16);
            float4 a0 = rxy[0], a1 = rxy[1], a2 = rxy[2], a3 = rxy[3];
            float4 c0 = ryx[0], c1 = ryx[1], c2 = ryx[2], c3 = ryx[3];
#pragma unroll
            for (int fi = 0; fi < 4; fi++) {
                const float* F = &flt[(fq * 4 + fi) * 180];
                float v01 = dot16(a0, a1, a2, a3, F + 1 * 20) + dot16(c0, c1, c2, c3, F + 3 * 20);
                float v02 = dot16(a0, a1, a2, a3, F + 2 * 20) + dot16(c0, c1, c2, c3, F + 6 * 20);
                float v12 = dot16(a0, a1, a2, a3, F + 5 * 20) + dot16(c0, c1, c2, c3, F + 7 * 20);
                size_t nrow = ((size_t)b * 16 + fq * 4 + fi) * KTOT;
                Bp[nrow + SEG01 + u] = f2bf(v01);
                Bp[nrow + SEG02 + u] = f2bf(v02);
                Bp[nrow + SEG12 + u] = f2bf(v12);
            }
        } else if (u < 528) {
            int x = u - NPAIR;                // diagonal element
            const float4* rxx = (const float4*)(inputs + (((size_t)b * 32 + x) * 32 + x) * 16);
            float4 a0 = rxx[0], a1 = rxx[1], a2 = rxx[2], a3 = rxx[3];
#pragma unroll
            for (int fi = 0; fi < 4; fi++) {
                const float* F = &flt[(fq * 4 + fi) * 180];
                float v0 = dot16(a0, a1, a2, a3, F + 0 * 20);
                float v4 = dot16(a0, a1, a2, a3, F + 4 * 20);
                float v8 = dot16(a0, a1, a2, a3, F + 8 * 20);
                size_t nrow = ((size_t)b * 16 + fq * 4 + fi) * KTOT;
                Bp[nrow + SEGD0 + x] = f2bf(v0);
                Bp[nrow + SEGD1 + x] = f2bf(v4);
                Bp[nrow + SEGD2 + x] = f2bf(v8);
            }
        } else if (ch == 8 && lane >= 16 && lane < 32) {
            int col = lane - 16;              // zero K-pad cols 1584..1599
#pragma unroll
            for (int fi = 0; fi < 4; fi++)
                Bp[((size_t)b * 16 + fq * 4 + fi) * KTOT + 1584 + col] = 0;
        }
    }
}

// ===== L2: split-K GEMM; last z-block per tile reduces part -> out (semaphore) ====
__global__ __launch_bounds__(256) void k_gemm(const unsigned short* __restrict__ A,
                                              const unsigned short* __restrict__ Bm,
                                              float* __restrict__ part,
                                              float* __restrict__ out,
                                              int* __restrict__ sem) {
    __shared__ __align__(16) unsigned short As[2][64 * 32];
    __shared__ __align__(16) unsigned short Bs[2][64 * 32];
    __shared__ int islast;
    int tid = threadIdx.x;
    int q0 = blockIdx.x * 64, n0 = blockIdx.y * 64, z = blockIdx.z;
    int k0 = z * KCH;
    int wave = tid >> 6, lane = tid & 63;
    int wm = wave & 1, wn = wave >> 1;
    int row16 = lane & 15, quad = lane >> 4;

    int srow = tid >> 2;
    int schunk = (tid & 3) ^ ((srow >> 1) & 3);
    const unsigned short* ga = A + (size_t)(q0 + srow) * KTOT + k0 + schunk * 8;
    const unsigned short* gb = Bm + (size_t)(n0 + srow) * KTOT + k0 + schunk * 8;
    char* lA = (char*)&As[0][0] + tid * 16;
    char* lB = (char*)&Bs[0][0] + tid * 16;

    f32x4 acc[2][2] = {};
    int fchunk = (quad ^ ((row16 >> 1) & 3)) * 8;

    gload_lds16(ga, lA);
    gload_lds16(gb, lB);
    for (int it = 0; it < NIT; ++it) {
        __syncthreads();
        if (it + 1 < NIT) {
            int nb = (it + 1) & 1;
            gload_lds16(ga + (it + 1) * 32, lA + nb * 64 * 32 * 2);
            gload_lds16(gb + (it + 1) * 32, lB + nb * 64 * 32 * 2);
        }
        int buf = it & 1;
        bf16x8 afr[2], bfr[2];
#pragma unroll
        for (int mi = 0; mi < 2; mi++)
            afr[mi] = *(const bf16x8*)&As[buf][(wm * 32 + mi * 16 + row16) * 32 + fchunk];
#pragma unroll
        for (int ni = 0; ni < 2; ni++)
            bfr[ni] = *(const bf16x8*)&Bs[buf][(wn * 32 + ni * 16 + row16) * 32 + fchunk];
#pragma unroll
        for (int mi = 0; mi < 2; mi++)
#pragma unroll
            for (int ni = 0; ni < 2; ni++)
                acc[mi][ni] = __builtin_amdgcn_mfma_f32_16x16x32_bf16(
                    afr[mi], bfr[ni], acc[mi][ni], 0, 0, 0);
    }

    // write this z-slice's partial tile
    float* pz = part + (size_t)z * (NQ * 512);
#pragma unroll
    for (int mi = 0; mi < 2; mi++)
#pragma unroll
        for (int ni = 0; ni < 2; ni++)
#pragma unroll
            for (int r = 0; r < 4; r++) {
                int q = q0 + wm * 32 + mi * 16 + quad * 4 + r;
                int n = n0 + wn * 32 + ni * 16 + row16;
                pz[q * 512 + n] = acc[mi][ni][r];
            }

    // split-K semaphore: last block for this (q0,n0) tile reduces to out
    __syncthreads();                               // all stores issued (vmcnt drained)
    if (tid == 0) {
        __threadfence();                           // publish slice to device scope
        int tileid = blockIdx.x * 8 + blockIdx.y;
        islast = (atomicAdd(&sem[tileid], 1) == ZSPLIT - 1);
        if (islast) __threadfence();               // acquire: invalidate stale cache
    }
    __syncthreads();
    if (islast) {
        int qr = tid >> 2, nc = tid & 3;           // 64 q-rows x 4 chunks of 16 n
        int q = q0 + qr;
        float4 s0 = {0,0,0,0}, s1 = s0, s2 = s0, s3 = s0;
#pragma unroll
        for (int z2 = 0; z2 < ZSPLIT; z2++) {
            const float4* p4 = (const float4*)(part + (size_t)z2 * (NQ * 512) + q * 512 + n0 + nc * 16);
            float4 b0 = p4[0], b1 = p4[1], b2 = p4[2], b3 = p4[3];
            s0.x += b0.x; s0.y += b0.y; s0.z += b0.z; s0.w += b0.w;
            s1.x += b1.x; s1.y += b1.y; s1.z += b1.z; s1.w += b1.w;
            s2.x += b2.x; s2.y += b2.y; s2.z += b2.z; s2.w += b2.w;
            s3.x += b3.x; s3.y += b3.y; s3.z += b3.z; s3.w += b3.w;
        }
        float4* orow = (float4*)(out + (size_t)((n0 >> 4) + nc) * (NQ * REL_D) + q * 16);
        orow[0] = s0; orow[1] = s1; orow[2] = s2; orow[3] = s3;
    }
}

extern "C" void kernel_launch(void* const* d_in, const int* in_sizes, int n_in,
                              void* d_out, int out_size, void* d_ws, size_t ws_size,
                              hipStream_t stream) {
    const float* inputs  = (const float*)d_in[0];   // (32,32,32,16)
    const float* logits  = (const float*)d_in[1];   // (512,32)
    const float* filters = (const float*)d_in[2];   // (16,3,3,16)
    float* out = (float*)d_out;                     // (32,512,16)

    char* ws = (char*)d_ws;
    unsigned short* Wp = (unsigned short*)ws;                    // 1,638,400 B
    unsigned short* Bp = (unsigned short*)(ws + 1638400);        // 1,638,400 B
    float*          part = (float*)(ws + 3276800);               // 5,242,880 B
    int*            sem  = (int*)(ws + 8519680);                 // 256 B

    k_front<<<NQ + 72, 1024, 0, stream>>>(logits, inputs, filters, Wp, Bp, sem);
    k_gemm<<<dim3(8, 8, ZSPLIT), 256, 0, stream>>>(Wp, Bp, part, out, sem);
}

// Round 11
// 81.155 us; speedup vs baseline: 1.1454x; 1.1454x over previous
//
#include <hip/hip_runtime.h>
#include <hip/hip_bf16.h>

#define N_OBJ   32
#define G_TOTAL 4960      // C(32,3)
#define NPAIR   496       // C(32,2)
#define KTOT    1600      // 3*496 (pairs) + 3*32 (diag) + 16 pad
#define SEG01   0
#define SEG02   496
#define SEG12   992
#define SEGD0   1488
#define SEGD1   1520
#define SEGD2   1552
#define N_FILT  16
#define REL_D   16
#define BATCH   32
#define NQ      512
#define ZSPLIT  10
#define KCH     160       // KTOT / ZSPLIT
#define NIT     5         // KCH / 32

typedef __attribute__((ext_vector_type(8))) short bf16x8;
typedef __attribute__((ext_vector_type(4))) float f32x4;

static __device__ inline unsigned short f2bf(float x) {
    union { float f; unsigned int u; } v; v.f = x;
    unsigned int r = v.u + 0x7fffu + ((v.u >> 16) & 1u);   // RNE
    return (unsigned short)(r >> 16);
}
static __device__ inline void gload_lds16(const void* g, void* l) {
    __builtin_amdgcn_global_load_lds(
        (const __attribute__((address_space(1))) unsigned int*)g,
        (__attribute__((address_space(3))) unsigned int*)(unsigned int)(uintptr_t)l,
        16, 0, 0);
}
// base index of pairs starting with x in lexicographic C(32,2) packing
static __device__ inline int pbase(int x) { return (x * (63 - x)) >> 1; }
// unrank lexicographic 2-combination of 32
static __device__ inline void unrank2(int u, int& x, int& y) {
    for (x = 0; x < 31; x++) { int len = 31 - x; if (u < len) break; u -= len; }
    y = x + 1 + u;
}
static __device__ inline float dot16(float4 a0, float4 a1, float4 a2, float4 a3,
                                     const float* F) {
    float4 f0 = *(const float4*)(F);
    float4 f1 = *(const float4*)(F + 4);
    float4 f2 = *(const float4*)(F + 8);
    float4 f3 = *(const float4*)(F + 12);
    float d = a0.x * f0.x + a0.y * f0.y + a0.z * f0.z + a0.w * f0.w;
    d += a1.x * f1.x + a1.y * f1.y + a1.z * f1.z + a1.w * f1.w;
    d += a2.x * f2.x + a2.y * f2.y + a2.z * f2.z + a2.w * f2.w;
    d += a3.x * f3.x + a3.y * f3.y + a3.z * f3.z + a3.w * f3.w;
    return d;
}

// ===== L1: normw rows (0..511) + folded pairconv (512..583, 4 sub-blocks each) ====
// W01[x,y] = sum_{c>y} exp(sp x*y*c); W02[x,z] = sum_{x<b<z}; W12[y,z] = sum_{a<y}
// total = sum of W01 segment (each combo counted once at its (a,b) pair).
__global__ __launch_bounds__(1024) void k_front(const float* __restrict__ logits,
                                                const float* __restrict__ inputs,
                                                const float* __restrict__ filters,
                                                unsigned short* __restrict__ Wp,
                                                unsigned short* __restrict__ Bp) {
    __shared__ __align__(16) char smem[11648];
    int t = threadIdx.x;
    int role = blockIdx.x;

    if (role < NQ) {
        float* sp  = (float*)smem;             // 32 floats
        float* red = (float*)(smem + 128);     // 8 floats
        float* Wf  = (float*)(smem + 192);     // 1600 floats
        int q = role;
        if (t < N_OBJ) {
            float x = logits[q * N_OBJ + t];
            float ex = __expf(x);
            sp[t] = (x > 15.f) ? x : __logf(1.f + ex);
        }
        __syncthreads();

        // pass A: 1488 independent range-sums, no atomics
#pragma unroll
        for (int rep = 0; rep < 2; rep++) {
            int idx = t + rep * 1024;
            if (idx < 3 * NPAIR) {
                int which = idx / NPAIR;
                int u = idx - which * NPAIR;
                int x, y; unrank2(u, x, y);
                float pxy = sp[x] * sp[y];
                float s = 0.f;
                if (which == 0) {                    // W01: c in (y, 32)
                    for (int c = y + 1; c < 32; c++) s += __expf(pxy * sp[c]);
                } else if (which == 1) {             // W02: b in (x, y)
                    for (int c = x + 1; c < y; c++)  s += __expf(pxy * sp[c]);
                } else {                             // W12: a in [0, x)
                    for (int c = 0; c < x; c++)      s += __expf(pxy * sp[c]);
                }
                Wf[which * NPAIR + u] = s;
            }
        }
        __syncthreads();

        // stage 2 (parallel roles): reduce total | diag marginals | pad zero
        if (t < 512) {
            float lsum = (t < NPAIR) ? Wf[t] : 0.f;
#pragma unroll
            for (int off = 32; off; off >>= 1) lsum += __shfl_down(lsum, off, 64);
            if ((t & 63) == 0) red[t >> 6] = lsum;
        } else if (t < 608) {
            int which = (t - 512) >> 5, idx = t & 31;
            float s = 0.f;
            if (which == 0) {                        // Wd0[a] = sum_{b>a} W01[a,b]
                int base = pbase(idx);
                for (int u = idx + 1; u < 32; u++) s += Wf[SEG01 + base + u - idx - 1];
                Wf[SEGD0 + idx] = s;
            } else if (which == 1) {                 // Wd1[b] = sum_{a<b} W01[a,b]
                for (int a2 = 0; a2 < idx; a2++) s += Wf[SEG01 + pbase(a2) + idx - a2 - 1];
                Wf[SEGD1 + idx] = s;
            } else {                                 // Wd2[c] = sum_{b<c} W12[b,c]
                for (int b2 = 0; b2 < idx; b2++) s += Wf[SEG12 + pbase(b2) + idx - b2 - 1];
                Wf[SEGD2 + idx] = s;
            }
        } else if (t < 624) {
            Wf[1584 + (t - 608)] = 0.f;              // K-pad
        }
        __syncthreads();

        // stage 3: normalize + pack + coalesced row write (800 uints)
        if (t < KTOT / 2) {
            float total = red[0] + red[1] + red[2] + red[3] +
                          red[4] + red[5] + red[6] + red[7];
            float inv = 1.f / total;
            unsigned int pk = (unsigned int)f2bf(Wf[2 * t] * inv) |
                              ((unsigned int)f2bf(Wf[2 * t + 1] * inv) << 16);
            ((unsigned int*)(Wp + (size_t)q * KTOT))[t] = pk;
        }
    } else {
        // ---------- folded pairconv: block covers 4 of the 256-thread work units ---
        float* flt = (float*)smem;            // 16*180 floats = 11520 B
        int role2 = role - NQ;                // 0..71
        if (t < 576) {
            int i4 = t * 4;
            int f = i4 / 144;
            int r = i4 - f * 144;
            *(float4*)&flt[f * 180 + (r >> 4) * 20 + (r & 15)] = *(const float4*)(filters + i4);
        }
        __syncthreads();

        int oldbid = role2 * 4 + (t >> 8);    // 0..287
        int tp = t & 255;
        int b = oldbid / 9, ch = oldbid - b * 9;
        int lane = tp & 63, fq = tp >> 6;     // 4 filter-quads x 64 items
        int u = ch * 64 + lane;
        if (u < NPAIR) {
            int x, y; unrank2(u, x, y);
            const float4* rxy = (const float4*)(inputs + (((size_t)b * 32 + x) * 32 + y) * 16);
            const float4* ryx = (const float4*)(inputs + (((size_t)b * 32 + y) * 32 + x) * 16);
            float4 a0 = rxy[0], a1 = rxy[1], a2 = rxy[2], a3 = rxy[3];
            float4 c0 = ryx[0], c1 = ryx[1], c2 = ryx[2], c3 = ryx[3];
#pragma unroll
            for (int fi = 0; fi < 4; fi++) {
                const float* F = &flt[(fq * 4 + fi) * 180];
                float v01 = dot16(a0, a1, a2, a3, F + 1 * 20) + dot16(c0, c1, c2, c3, F + 3 * 20);
                float v02 = dot16(a0, a1, a2, a3, F + 2 * 20) + dot16(c0, c1, c2, c3, F + 6 * 20);
                float v12 = dot16(a0, a1, a2, a3, F + 5 * 20) + dot16(c0, c1, c2, c3, F + 7 * 20);
                size_t nrow = ((size_t)b * 16 + fq * 4 + fi) * KTOT;
                Bp[nrow + SEG01 + u] = f2bf(v01);
                Bp[nrow + SEG02 + u] = f2bf(v02);
                Bp[nrow + SEG12 + u] = f2bf(v12);
            }
        } else if (u < 528) {
            int x = u - NPAIR;                // diagonal element
            const float4* rxx = (const float4*)(inputs + (((size_t)b * 32 + x) * 32 + x) * 16);
            float4 a0 = rxx[0], a1 = rxx[1], a2 = rxx[2], a3 = rxx[3];
#pragma unroll
            for (int fi = 0; fi < 4; fi++) {
                const float* F = &flt[(fq * 4 + fi) * 180];
                float v0 = dot16(a0, a1, a2, a3, F + 0 * 20);
                float v4 = dot16(a0, a1, a2, a3, F + 4 * 20);
                float v8 = dot16(a0, a1, a2, a3, F + 8 * 20);
                size_t nrow = ((size_t)b * 16 + fq * 4 + fi) * KTOT;
                Bp[nrow + SEGD0 + x] = f2bf(v0);
                Bp[nrow + SEGD1 + x] = f2bf(v4);
                Bp[nrow + SEGD2 + x] = f2bf(v8);
            }
        } else if (ch == 8 && lane >= 16 && lane < 32) {
            int col = lane - 16;              // zero K-pad cols 1584..1599
#pragma unroll
            for (int fi = 0; fi < 4; fi++)
                Bp[((size_t)b * 16 + fq * 4 + fi) * KTOT + 1584 + col] = 0;
        }
    }
}

// ===== L2: part[z] = Wp(512xK) x Bp^T tile, split-K (640 blocks), no atomics ======
__global__ __launch_bounds__(256) void k_gemm(const unsigned short* __restrict__ A,
                                              const unsigned short* __restrict__ Bm,
                                              float* __restrict__ part) {
    __shared__ __align__(16) unsigned short As[2][64 * 32];
    __shared__ __align__(16) unsigned short Bs[2][64 * 32];
    int tid = threadIdx.x;
    int q0 = blockIdx.x * 64, n0 = blockIdx.y * 64, z = blockIdx.z;
    int k0 = z * KCH;
    int wave = tid >> 6, lane = tid & 63;
    int wm = wave & 1, wn = wave >> 1;
    int row16 = lane & 15, quad = lane >> 4;

    int srow = tid >> 2;
    int schunk = (tid & 3) ^ ((srow >> 1) & 3);
    const unsigned short* ga = A + (size_t)(q0 + srow) * KTOT + k0 + schunk * 8;
    const unsigned short* gb = Bm + (size_t)(n0 + srow) * KTOT + k0 + schunk * 8;
    char* lA = (char*)&As[0][0] + tid * 16;
    char* lB = (char*)&Bs[0][0] + tid * 16;

    f32x4 acc[2][2] = {};
    int fchunk = (quad ^ ((row16 >> 1) & 3)) * 8;

    gload_lds16(ga, lA);
    gload_lds16(gb, lB);
    for (int it = 0; it < NIT; ++it) {
        __syncthreads();
        if (it + 1 < NIT) {
            int nb = (it + 1) & 1;
            gload_lds16(ga + (it + 1) * 32, lA + nb * 64 * 32 * 2);
            gload_lds16(gb + (it + 1) * 32, lB + nb * 64 * 32 * 2);
        }
        int buf = it & 1;
        bf16x8 afr[2], bfr[2];
#pragma unroll
        for (int mi = 0; mi < 2; mi++)
            afr[mi] = *(const bf16x8*)&As[buf][(wm * 32 + mi * 16 + row16) * 32 + fchunk];
#pragma unroll
        for (int ni = 0; ni < 2; ni++)
            bfr[ni] = *(const bf16x8*)&Bs[buf][(wn * 32 + ni * 16 + row16) * 32 + fchunk];
#pragma unroll
        for (int mi = 0; mi < 2; mi++)
#pragma unroll
            for (int ni = 0; ni < 2; ni++)
                acc[mi][ni] = __builtin_amdgcn_mfma_f32_16x16x32_bf16(
                    afr[mi], bfr[ni], acc[mi][ni], 0, 0, 0);
    }

    float* pz = part + (size_t)z * (NQ * 512);
#pragma unroll
    for (int mi = 0; mi < 2; mi++)
#pragma unroll
        for (int ni = 0; ni < 2; ni++)
#pragma unroll
            for (int r = 0; r < 4; r++) {
                int q = q0 + wm * 32 + mi * 16 + quad * 4 + r;
                int n = n0 + wn * 32 + ni * 16 + row16;
                pz[q * 512 + n] = acc[mi][ni][r];
            }
}

// ===== L3: reduce 10 split-K partials, remap to out[b][q][r] ======================
__global__ __launch_bounds__(256) void k_reduce(const float* __restrict__ part,
                                                float* __restrict__ out) {
    int gid = blockIdx.x * 256 + threadIdx.x;   // 65536 threads
    int q = gid >> 7;
    int n = (gid & 127) * 4;
    float4 a = *(const float4*)(part + q * 512 + n);
#pragma unroll
    for (int zz = 1; zz < ZSPLIT; zz++) {
        float4 b4 = *(const float4*)(part + (size_t)zz * (NQ * 512) + q * 512 + n);
        a.x += b4.x; a.y += b4.y; a.z += b4.z; a.w += b4.w;
    }
    *(float4*)(out + (size_t)(n >> 4) * (NQ * REL_D) + q * 16 + (n & 15)) = a;
}

extern "C" void kernel_launch(void* const* d_in, const int* in_sizes, int n_in,
                              void* d_out, int out_size, void* d_ws, size_t ws_size,
                              hipStream_t stream) {
    const float* inputs  = (const float*)d_in[0];   // (32,32,32,16)
    const float* logits  = (const float*)d_in[1];   // (512,32)
    const float* filters = (const float*)d_in[2];   // (16,3,3,16)
    float* out = (float*)d_out;                     // (32,512,16)

    char* ws = (char*)d_ws;
    unsigned short* Wp = (unsigned short*)ws;                    //  1,638,400 B
    unsigned short* Bp = (unsigned short*)(ws + 1638400);        //  1,638,400 B
    float*          part = (float*)(ws + 3276800);               // 10,485,760 B

    k_front<<<NQ + 72, 1024, 0, stream>>>(logits, inputs, filters, Wp, Bp);
    k_gemm<<<dim3(8, 8, ZSPLIT), 256, 0, stream>>>(Wp, Bp, part);
    k_reduce<<<NQ * 512 / 4 / 256, 256, 0, stream>>>(part, out);
}

// Round 12
// 80.904 us; speedup vs baseline: 1.1489x; 1.0031x over previous
//
#include <hip/hip_runtime.h>
#include <hip/hip_bf16.h>

#define N_OBJ   32
#define G_TOTAL 4960      // C(32,3)
#define NPAIR   496       // C(32,2)
#define KTOT    1600      // 3*496 (pairs) + 3*32 (diag) + 16 pad
#define SEG01   0
#define SEG02   496
#define SEG12   992
#define SEGD0   1488
#define SEGD1   1520
#define SEGD2   1552
#define N_FILT  16
#define REL_D   16
#define BATCH   32
#define NQ      512
#define ZSPLIT  10
#define KCH     160       // KTOT / ZSPLIT
#define NIT     5         // KCH / 32

typedef __attribute__((ext_vector_type(8))) short bf16x8;
typedef __attribute__((ext_vector_type(4))) float f32x4;

static __device__ inline unsigned short f2bf(float x) {
    union { float f; unsigned int u; } v; v.f = x;
    unsigned int r = v.u + 0x7fffu + ((v.u >> 16) & 1u);   // RNE
    return (unsigned short)(r >> 16);
}
static __device__ inline void gload_lds16(const void* g, void* l) {
    __builtin_amdgcn_global_load_lds(
        (const __attribute__((address_space(1))) unsigned int*)g,
        (__attribute__((address_space(3))) unsigned int*)(unsigned int)(uintptr_t)l,
        16, 0, 0);
}
// base index of pairs starting with x in lexicographic C(32,2) packing
static __device__ inline int pbase(int x) { return (x * (63 - x)) >> 1; }
// unrank lexicographic 2-combination of 32
static __device__ inline void unrank2(int u, int& x, int& y) {
    for (x = 0; x < 31; x++) { int len = 31 - x; if (u < len) break; u -= len; }
    y = x + 1 + u;
}
static __device__ inline float dot16(float4 a0, float4 a1, float4 a2, float4 a3,
                                     const float* F) {
    float4 f0 = *(const float4*)(F);
    float4 f1 = *(const float4*)(F + 4);
    float4 f2 = *(const float4*)(F + 8);
    float4 f3 = *(const float4*)(F + 12);
    float d = a0.x * f0.x + a0.y * f0.y + a0.z * f0.z + a0.w * f0.w;
    d += a1.x * f1.x + a1.y * f1.y + a1.z * f1.z + a1.w * f1.w;
    d += a2.x * f2.x + a2.y * f2.y + a2.z * f2.z + a2.w * f2.w;
    d += a3.x * f3.x + a3.y * f3.y + a3.z * f3.z + a3.w * f3.w;
    return d;
}

// ===== L1: normw rows (0..511) + folded pairconv (512..583, 4 sub-blocks each) ====
// W01[x,y] = sum_{c>y} exp(sp x*y*c); W02[x,z] = sum_{x<b<z}; W12[y,z] = sum_{a<y}
// total = sum of W01 segment (each combo counted once at its (a,b) pair).
__global__ __launch_bounds__(1024) void k_front(const float* __restrict__ logits,
                                                const float* __restrict__ inputs,
                                                const float* __restrict__ filters,
                                                unsigned short* __restrict__ Wp,
                                                unsigned short* __restrict__ Bp) {
    __shared__ __align__(16) char smem[11648];
    int t = threadIdx.x;
    int role = blockIdx.x;

    if (role < NQ) {
        float* sp  = (float*)smem;             // 32 floats
        float* red = (float*)(smem + 128);     // 8 floats
        float* Wf  = (float*)(smem + 192);     // 1600 floats
        int q = role;
        if (t < N_OBJ) {
            float x = logits[q * N_OBJ + t];
            float ex = __expf(x);
            sp[t] = (x > 15.f) ? x : __logf(1.f + ex);
        }
        __syncthreads();

        // pass A: 1488 independent range-sums, fully unrolled + predicated
        // (no runtime-bounded serial loop: 8 batched b128 broadcasts + 32 exps)
#pragma unroll
        for (int rep = 0; rep < 2; rep++) {
            int idx = t + rep * 1024;
            if (idx < 3 * NPAIR) {
                int which = idx / NPAIR;
                int u = idx - which * NPAIR;
                int x, y; unrank2(u, x, y);
                float pxy = sp[x] * sp[y];
                int lo, hi;                          // include c with lo <= c < hi
                if (which == 0)      { lo = y + 1; hi = 32; }   // W01
                else if (which == 1) { lo = x + 1; hi = y;  }   // W02
                else                 { lo = 0;     hi = x;  }   // W12
                const float4* sp4 = (const float4*)sp;
                float s = 0.f;
#pragma unroll
                for (int cb = 0; cb < 8; cb++) {
                    float4 v = sp4[cb];
                    int c0 = cb * 4;
                    s += (c0 + 0 >= lo && c0 + 0 < hi) ? __expf(pxy * v.x) : 0.f;
                    s += (c0 + 1 >= lo && c0 + 1 < hi) ? __expf(pxy * v.y) : 0.f;
                    s += (c0 + 2 >= lo && c0 + 2 < hi) ? __expf(pxy * v.z) : 0.f;
                    s += (c0 + 3 >= lo && c0 + 3 < hi) ? __expf(pxy * v.w) : 0.f;
                }
                Wf[which * NPAIR + u] = s;
            }
        }
        __syncthreads();

        // stage 2 (parallel roles): reduce total | diag marginals | pad zero
        if (t < 512) {
            float lsum = (t < NPAIR) ? Wf[t] : 0.f;
#pragma unroll
            for (int off = 32; off; off >>= 1) lsum += __shfl_down(lsum, off, 64);
            if ((t & 63) == 0) red[t >> 6] = lsum;
        } else if (t < 608) {
            int which = (t - 512) >> 5, idx = t & 31;
            float s = 0.f;
            if (which == 0) {                        // Wd0[a] = sum_{b>a} W01[a,b]
                int base = pbase(idx);
                for (int u = idx + 1; u < 32; u++) s += Wf[SEG01 + base + u - idx - 1];
                Wf[SEGD0 + idx] = s;
            } else if (which == 1) {                 // Wd1[b] = sum_{a<b} W01[a,b]
                for (int a2 = 0; a2 < idx; a2++) s += Wf[SEG01 + pbase(a2) + idx - a2 - 1];
                Wf[SEGD1 + idx] = s;
            } else {                                 // Wd2[c] = sum_{b<c} W12[b,c]
                for (int b2 = 0; b2 < idx; b2++) s += Wf[SEG12 + pbase(b2) + idx - b2 - 1];
                Wf[SEGD2 + idx] = s;
            }
        } else if (t < 624) {
            Wf[1584 + (t - 608)] = 0.f;              // K-pad
        }
        __syncthreads();

        // stage 3: normalize + pack + coalesced row write (800 uints)
        if (t < KTOT / 2) {
            float total = red[0] + red[1] + red[2] + red[3] +
                          red[4] + red[5] + red[6] + red[7];
            float inv = 1.f / total;
            unsigned int pk = (unsigned int)f2bf(Wf[2 * t] * inv) |
                              ((unsigned int)f2bf(Wf[2 * t + 1] * inv) << 16);
            ((unsigned int*)(Wp + (size_t)q * KTOT))[t] = pk;
        }
    } else {
        // ---------- folded pairconv: block covers 4 of the 256-thread work units ---
        float* flt = (float*)smem;            // 16*180 floats = 11520 B
        int role2 = role - NQ;                // 0..71
        if (t < 576) {
            int i4 = t * 4;
            int f = i4 / 144;
            int r = i4 - f * 144;
            *(float4*)&flt[f * 180 + (r >> 4) * 20 + (r & 15)] = *(const float4*)(filters + i4);
        }
        __syncthreads();

        int oldbid = role2 * 4 + (t >> 8);    // 0..287
        int tp = t & 255;
        int b = oldbid / 9, ch = oldbid - b * 9;
        int lane = tp & 63, fq = tp >> 6;     // 4 filter-quads x 64 items
        int u = ch * 64 + lane;
        if (u < NPAIR) {
            int x, y; unrank2(u, x, y);
            const float4* rxy = (const float4*)(inputs + (((size_t)b * 32 + x) * 32 + y) * 16);
            const float4* ryx = (const float4*)(inputs + (((size_t)b * 32 + y) * 32 + x) * 16);
            float4 a0 = rxy[0], a1 = rxy[1], a2 = rxy[2], a3 = rxy[3];
            float4 c0 = ryx[0], c1 = ryx[1], c2 = ryx[2], c3 = ryx[3];
#pragma unroll
            for (int fi = 0; fi < 4; fi++) {
                const float* F = &flt[(fq * 4 + fi) * 180];
                float v01 = dot16(a0, a1, a2, a3, F + 1 * 20) + dot16(c0, c1, c2, c3, F + 3 * 20);
                float v02 = dot16(a0, a1, a2, a3, F + 2 * 20) + dot16(c0, c1, c2, c3, F + 6 * 20);
                float v12 = dot16(a0, a1, a2, a3, F + 5 * 20) + dot16(c0, c1, c2, c3, F + 7 * 20);
                size_t nrow = ((size_t)b * 16 + fq * 4 + fi) * KTOT;
                Bp[nrow + SEG01 + u] = f2bf(v01);
                Bp[nrow + SEG02 + u] = f2bf(v02);
                Bp[nrow + SEG12 + u] = f2bf(v12);
            }
        } else if (u < 528) {
            int x = u - NPAIR;                // diagonal element
            const float4* rxx = (const float4*)(inputs + (((size_t)b * 32 + x) * 32 + x) * 16);
            float4 a0 = rxx[0], a1 = rxx[1], a2 = rxx[2], a3 = rxx[3];
#pragma unroll
            for (int fi = 0; fi < 4; fi++) {
                const float* F = &flt[(fq * 4 + fi) * 180];
                float v0 = dot16(a0, a1, a2, a3, F + 0 * 20);
                float v4 = dot16(a0, a1, a2, a3, F + 4 * 20);
                float v8 = dot16(a0, a1, a2, a3, F + 8 * 20);
                size_t nrow = ((size_t)b * 16 + fq * 4 + fi) * KTOT;
                Bp[nrow + SEGD0 + x] = f2bf(v0);
                Bp[nrow + SEGD1 + x] = f2bf(v4);
                Bp[nrow + SEGD2 + x] = f2bf(v8);
            }
        } else if (ch == 8 && lane >= 16 && lane < 32) {
            int col = lane - 16;              // zero K-pad cols 1584..1599
#pragma unroll
            for (int fi = 0; fi < 4; fi++)
                Bp[((size_t)b * 16 + fq * 4 + fi) * KTOT + 1584 + col] = 0;
        }
    }
}

// ===== L2: part[z] = Wp(512xK) x Bp^T tile, split-K (640 blocks), no atomics ======
__global__ __launch_bounds__(256) void k_gemm(const unsigned short* __restrict__ A,
                                              const unsigned short* __restrict__ Bm,
                                              float* __restrict__ part) {
    __shared__ __align__(16) unsigned short As[2][64 * 32];
    __shared__ __align__(16) unsigned short Bs[2][64 * 32];
    int tid = threadIdx.x;
    int q0 = blockIdx.x * 64, n0 = blockIdx.y * 64, z = blockIdx.z;
    int k0 = z * KCH;
    int wave = tid >> 6, lane = tid & 63;
    int wm = wave & 1, wn = wave >> 1;
    int row16 = lane & 15, quad = lane >> 4;

    int srow = tid >> 2;
    int schunk = (tid & 3) ^ ((srow >> 1) & 3);
    const unsigned short* ga = A + (size_t)(q0 + srow) * KTOT + k0 + schunk * 8;
    const unsigned short* gb = Bm + (size_t)(n0 + srow) * KTOT + k0 + schunk * 8;
    char* lA = (char*)&As[0][0] + tid * 16;
    char* lB = (char*)&Bs[0][0] + tid * 16;

    f32x4 acc[2][2] = {};
    int fchunk = (quad ^ ((row16 >> 1) & 3)) * 8;

    gload_lds16(ga, lA);
    gload_lds16(gb, lB);
    for (int it = 0; it < NIT; ++it) {
        __syncthreads();
        if (it + 1 < NIT) {
            int nb = (it + 1) & 1;
            gload_lds16(ga + (it + 1) * 32, lA + nb * 64 * 32 * 2);
            gload_lds16(gb + (it + 1) * 32, lB + nb * 64 * 32 * 2);
        }
        int buf = it & 1;
        bf16x8 afr[2], bfr[2];
#pragma unroll
        for (int mi = 0; mi < 2; mi++)
            afr[mi] = *(const bf16x8*)&As[buf][(wm * 32 + mi * 16 + row16) * 32 + fchunk];
#pragma unroll
        for (int ni = 0; ni < 2; ni++)
            bfr[ni] = *(const bf16x8*)&Bs[buf][(wn * 32 + ni * 16 + row16) * 32 + fchunk];
#pragma unroll
        for (int mi = 0; mi < 2; mi++)
#pragma unroll
            for (int ni = 0; ni < 2; ni++)
                acc[mi][ni] = __builtin_amdgcn_mfma_f32_16x16x32_bf16(
                    afr[mi], bfr[ni], acc[mi][ni], 0, 0, 0);
    }

    float* pz = part + (size_t)z * (NQ * 512);
#pragma unroll
    for (int mi = 0; mi < 2; mi++)
#pragma unroll
        for (int ni = 0; ni < 2; ni++)
#pragma unroll
            for (int r = 0; r < 4; r++) {
                int q = q0 + wm * 32 + mi * 16 + quad * 4 + r;
                int n = n0 + wn * 32 + ni * 16 + row16;
                pz[q * 512 + n] = acc[mi][ni][r];
            }
}

// ===== L3: reduce 10 split-K partials, remap to out[b][q][r] ======================
__global__ __launch_bounds__(256) void k_reduce(const float* __restrict__ part,
                                                float* __restrict__ out) {
    int gid = blockIdx.x * 256 + threadIdx.x;   // 65536 threads
    int q = gid >> 7;
    int n = (gid & 127) * 4;
    float4 a = *(const float4*)(part + q * 512 + n);
#pragma unroll
    for (int zz = 1; zz < ZSPLIT; zz++) {
        float4 b4 = *(const float4*)(part + (size_t)zz * (NQ * 512) + q * 512 + n);
        a.x += b4.x; a.y += b4.y; a.z += b4.z; a.w += b4.w;
    }
    *(float4*)(out + (size_t)(n >> 4) * (NQ * REL_D) + q * 16 + (n & 15)) = a;
}

extern "C" void kernel_launch(void* const* d_in, const int* in_sizes, int n_in,
                              void* d_out, int out_size, void* d_ws, size_t ws_size,
                              hipStream_t stream) {
    const float* inputs  = (const float*)d_in[0];   // (32,32,32,16)
    const float* logits  = (const float*)d_in[1];   // (512,32)
    const float* filters = (const float*)d_in[2];   // (16,3,3,16)
    float* out = (float*)d_out;                     // (32,512,16)

    char* ws = (char*)d_ws;
    unsigned short* Wp = (unsigned short*)ws;                    //  1,638,400 B
    unsigned short* Bp = (unsigned short*)(ws + 1638400);        //  1,638,400 B
    float*          part = (float*)(ws + 3276800);               // 10,485,760 B

    k_front<<<NQ + 72, 1024, 0, stream>>>(logits, inputs, filters, Wp, Bp);
    k_gemm<<<dim3(8, 8, ZSPLIT), 256, 0, stream>>>(Wp, Bp, part);
    k_reduce<<<NQ * 512 / 4 / 256, 256, 0, stream>>>(part, out);
}